// Round 9
// baseline (56693.243 us; speedup 1.0000x reference)
//
#include <hip/hip_runtime.h>

#define TT 1024
#define BB 64
#define HH 512
#define DD 512
#define NBLK 256
#define NTHR 512
#define NGRP 8           // 8 batch groups x 8 rows; 32 blocks per group

// ---------------- ws layout (32-bit words), total 4,562,944 words = 18,251,776 B (== R7/R8, proven)
#define W0T4_OFF 0               // [256 kq][2048 R][4]  transposed-packed W0
#define W1T4_OFF 2097152         // same for W1
#define H0_OFF   4194304         // [64 b][512]  h0 single-buffered
#define H1_OFF   4227072         // [64 b][512]
#define Z0_OFF   4259840         // [8 grp][8 bi][2048]
#define Z1_OFF   4390912         // [8 grp][8 bi][2048]
#define HWZ_OFF  4521984         // [8 grp][8 bi][512]
#define FLG_OFF  4554752         // [8 grp][32 slot][32 words]  (128B stride)

// ======== cross-block access: relaxed agent-scope atomics (MALL-coherent) ========
__device__ __forceinline__ float ldg_cg(const float* p) {
    return __hip_atomic_load(p, __ATOMIC_RELAXED, __HIP_MEMORY_SCOPE_AGENT);
}
__device__ __forceinline__ void stg_cg(float* p, float v) {
    __hip_atomic_store(p, v, __ATOMIC_RELAXED, __HIP_MEMORY_SCOPE_AGENT);
}
__device__ __forceinline__ float4 ldg_cg4(const float* p) {
    const unsigned long long* q = (const unsigned long long*)p;
    unsigned long long a = __hip_atomic_load(q,     __ATOMIC_RELAXED, __HIP_MEMORY_SCOPE_AGENT);
    unsigned long long b = __hip_atomic_load(q + 1, __ATOMIC_RELAXED, __HIP_MEMORY_SCOPE_AGENT);
    float4 v;
    ((unsigned long long*)&v)[0] = a;
    ((unsigned long long*)&v)[1] = b;
    return v;
}
__device__ __forceinline__ unsigned ldg_cgu(const unsigned* p) {
    return __hip_atomic_load(p, __ATOMIC_RELAXED, __HIP_MEMORY_SCOPE_AGENT);
}

// ======== group barrier: 32 blocks, flag-array, RELEASE-published (R7-proven) ========
__device__ __forceinline__ void group_barrier(unsigned* gfl, unsigned tgt, int slot, int tid)
{
    __syncthreads();
    if (tid == 0)
        __hip_atomic_store(&gfl[slot * 32], tgt, __ATOMIC_RELEASE, __HIP_MEMORY_SCOPE_AGENT);
    if (tid < 32) {
        while (ldg_cgu(&gfl[tid * 32]) < tgt) __builtin_amdgcn_s_sleep(1);
    }
    __syncthreads();
}

// ---------------- init: transpose-pack weights + zero h-state + flags ----------------
__global__ void ln_lstm_init_kernel(const float* __restrict__ W0, const float* __restrict__ W1,
                                    float* __restrict__ ws)
{
    const int stride = gridDim.x * blockDim.x;
    const int idx = blockIdx.x * blockDim.x + threadIdx.x;
    for (int i = idx; i < 2048 * 256; i += stride) {
        const int R = i & 2047, kq = i >> 11;
        const float4 v0 = *(const float4*)&W0[(size_t)R * 1024 + kq * 4];
        const float4 v1 = *(const float4*)&W1[(size_t)R * 1024 + kq * 4];
        *(float4*)&ws[W0T4_OFF + ((size_t)kq * 2048 + R) * 4] = v0;
        *(float4*)&ws[W1T4_OFF + ((size_t)kq * 2048 + R) * 4] = v1;
    }
    for (int i = idx; i < 65536; i += stride) ws[H0_OFF + i] = 0.f;    // h0 + h1
    unsigned* uw = (unsigned*)ws;
    for (int i = idx; i < 8192; i += stride) uw[FLG_OFF + i] = 0u;     // barrier flags
}

// ---------------- full-K GEMV: 64 rows x 8 batches; K eighth'd across 8 waves --------
// wave bq owns K-slice [bq*128, +128); lane r = row. After zr exchange, thread
// (bi_out=tid>>6, r=tid&63) holds z[row=R0+r, batch=bi_out] and stores it.
__device__ __forceinline__ void gemv_k8(const float4* __restrict__ wt, const float* __restrict__ inT,
                                        float* __restrict__ zr, int bq, int r, int Rrow,
                                        int bi_out, float& z)
{
    float a[8];
#pragma unroll
    for (int i = 0; i < 8; ++i) a[i] = 0.f;
    const float4* wp = wt + (size_t)(bq * 32) * 2048 + Rrow;
    const float* ib = inT + bq * 128;
#pragma unroll
    for (int c = 0; c < 2; ++c) {
        float4 w[16];
#pragma unroll
        for (int i = 0; i < 16; ++i) w[i] = wp[(size_t)(c * 16 + i) * 2048];
#pragma unroll
        for (int i = 0; i < 16; ++i) {
            const int kk = c * 64 + i * 4;
#pragma unroll
            for (int bi = 0; bi < 8; ++bi) {
                const float4 iv = *(const float4*)&ib[bi * 1024 + kk];   // LDS broadcast
                a[bi] += w[i].x * iv.x + w[i].y * iv.y + w[i].z * iv.z + w[i].w * iv.w;
            }
        }
    }
#pragma unroll
    for (int bi = 0; bi < 8; ++bi) zr[bq * 512 + bi * 64 + r] = a[bi];
    __syncthreads();
    z = 0.f;
#pragma unroll
    for (int w2 = 0; w2 < 8; ++w2) z += zr[w2 * 512 + bi_out * 64 + r];
}

// ---------------- block-local reductions (512 threads / 8 waves) ----------------
__device__ __forceinline__ void block_reduce8(float v[8], float* sred, int tid)
{
#pragma unroll
    for (int off = 32; off > 0; off >>= 1)
#pragma unroll
        for (int k = 0; k < 8; ++k) v[k] += __shfl_down(v[k], off, 64);
    __syncthreads();
    if ((tid & 63) == 0) {
        const int wv = tid >> 6;
#pragma unroll
        for (int k = 0; k < 8; ++k) sred[k * 8 + wv] = v[k];
    }
    __syncthreads();
#pragma unroll
    for (int k = 0; k < 8; ++k) {
        float s = 0.f;
#pragma unroll
        for (int i = 0; i < 8; ++i) s += sred[k * 8 + i];
        v[k] = s;
    }
}
__device__ __forceinline__ void block_reduce2(float& s1, float& s2, float* sred, int tid)
{
#pragma unroll
    for (int off = 32; off > 0; off >>= 1) {
        s1 += __shfl_down(s1, off, 64);
        s2 += __shfl_down(s2, off, 64);
    }
    __syncthreads();
    if ((tid & 63) == 0) {
        const int wv = tid >> 6;
        sred[wv] = s1; sred[8 + wv] = s2;
    }
    __syncthreads();
    s1 = 0.f; s2 = 0.f;
#pragma unroll
    for (int i = 0; i < 8; ++i) { s1 += sred[i]; s2 += sred[8 + i]; }
}

// ---------------- whole LSTM cell for one batch (512 threads, 1 elem/thread) ---------
__device__ __forceinline__ void cell(const float* __restrict__ zg, const float* __restrict__ gb,
                                     const float* __restrict__ lng, const float* __restrict__ lnb,
                                     float& cc, float* __restrict__ hws_b, float& hv,
                                     float* sred, int tid)
{
    float z[4];
#pragma unroll
    for (int g = 0; g < 4; ++g)
        z[g] = ldg_cg(zg + g * 512 + tid) + gb[g * 512 + tid];
    float st[8];
#pragma unroll
    for (int g = 0; g < 4; ++g) { st[g] = z[g]; st[4 + g] = z[g] * z[g]; }
    block_reduce8(st, sred, tid);
    float act[4];
#pragma unroll
    for (int g = 0; g < 4; ++g) {
        const float mu = st[g] * (1.f / 512.f);
        const float rs = rsqrtf(st[4 + g] * (1.f / 512.f) - mu * mu + 1e-5f);
        const float a = (z[g] - mu) * rs * lng[g * 512 + tid] + lnb[g * 512 + tid];
        act[g] = (g == 2) ? tanhf(a) : 1.f / (1.f + expf(-a));
    }
    const float cn = act[1] * cc + act[0] * act[2];   // f*c + i*g
    cc = cn;
    float s1 = cn, s2 = cn * cn;
    block_reduce2(s1, s2, sred, tid);
    const float mu = s1 * (1.f / 512.f);
    const float rs = rsqrtf(s2 * (1.f / 512.f) - mu * mu + 1e-5f);
    const float h = act[3] * tanhf((cn - mu) * rs * lng[2048 + tid] + lnb[2048 + tid]);
    stg_cg(hws_b + tid, h);
    hv = h;
}

__global__ __launch_bounds__(NTHR, 1)
void LayerNormLSTMStack_55508157333865_kernel(
    const float* __restrict__ x,
    const float* __restrict__ W0, const float* __restrict__ gb0,
    const float* __restrict__ lng0, const float* __restrict__ lnb0,
    const float* __restrict__ W1, const float* __restrict__ gb1,
    const float* __restrict__ lng1, const float* __restrict__ lnb1,
    const float* __restrict__ hwW, const float* __restrict__ hwb,
    float* __restrict__ out, float* __restrict__ ws)
{
    __shared__ __align__(16) float inT[8 * 1024];   // 32 KB [bi][k]
    __shared__ __align__(16) float zr[8 * 512];     // 16 KB per-wave K-partials
    __shared__ float sred[64];
    __shared__ float hwred[512];

    const int tid = threadIdx.x;
    const int grp = blockIdx.x >> 5;        // batch group (8 rows)
    const int bg  = blockIdx.x & 31;        // slot in group
    const int bb0 = grp * 8;
    const int r = tid & 63, bq = tid >> 6;  // lane = row; wave = K-slice / out-batch
    const int R0 = bg * 64;                 // this block's 64 GEMV rows

    const float4* w0t = (const float4*)(ws + W0T4_OFF);
    const float4* w1t = (const float4*)(ws + W1T4_OFF);
    float* h0ws  = ws + H0_OFF;
    float* h1ws  = ws + H1_OFF;
    float* z0g   = ws + Z0_OFF + grp * 16384;
    float* z1g   = ws + Z1_OFF + grp * 16384;
    float* hwzg  = ws + HWZ_OFF + grp * 4096;
    unsigned* gfl = (unsigned*)ws + FLG_OFF + grp * 1024;

    float c0 = 0.f, c1 = 0.f;
    float hv0 = 0.f;                        // h0(t) for this block's batch (bg<8), kept in regs
    unsigned ph = 0;
    const size_t OUT_SZ = (size_t)BB * TT * HH;
    const int sbi = tid >> 6, part = tid & 63;   // staging: row sbi, lane part
    const float hwb_r = hwb[tid];

    // ================= prologue: gemv0(0) ; cell0(0) =================
    {
        const float* xp = x + ((size_t)(bb0 + sbi) * TT + 0) * DD;
        float* d = &inT[sbi * 1024];
        *(float4*)&d[part * 4]       = *(const float4*)&xp[part * 4];
        *(float4*)&d[256 + part * 4] = *(const float4*)&xp[256 + part * 4];
        *(float4*)&d[512 + part * 4] = make_float4(0.f, 0.f, 0.f, 0.f);   // h0(-1)=0
        *(float4*)&d[768 + part * 4] = make_float4(0.f, 0.f, 0.f, 0.f);
    }
    __syncthreads();
    {
        float z;
        gemv_k8(w0t, inT, zr, bq, r, R0 + r, bq, z);
        stg_cg(z0g + (size_t)bq * 2048 + R0 + r, z);
    }
    group_barrier(gfl, ++ph, bg, tid);
    if (bg < 8)
        cell(z0g + (size_t)bg * 2048, gb0, lng0, lnb0, c0, h0ws + (size_t)(bb0 + bg) * 512, hv0, sred, tid);
    group_barrier(gfl, ++ph, bg, tid);

    for (int t = 0; t < TT; ++t) {
        const bool more = (t + 1 < TT);

        // ================= P_A: gemv1(t) + hw(t) + gemv0(t+1) =================
        // stage inT = [h0(t) | h1(t-1)]  (conflict-free: lane writes consecutive float4)
        {
            const float* hp0 = h0ws + (size_t)(bb0 + sbi) * 512;
            float* d = &inT[sbi * 1024];
            *(float4*)&d[part * 4]       = ldg_cg4(hp0 + part * 4);
            *(float4*)&d[256 + part * 4] = ldg_cg4(hp0 + 256 + part * 4);
            const float* hp1 = h1ws + (size_t)(bb0 + sbi) * 512;
            *(float4*)&d[512 + part * 4] = ldg_cg4(hp1 + part * 4);
            *(float4*)&d[768 + part * 4] = ldg_cg4(hp1 + 256 + part * 4);
        }
        __syncthreads();
        {
            float z;
            gemv_k8(w1t, inT, zr, bq, r, R0 + r, bq, z);
            stg_cg(z1g + (size_t)bq * 2048 + R0 + r, z);
        }
        // highway rows [bg*16, +16) x 8 batches; 4 threads per output (K quarters)
        {
            const int rh = tid & 15, bi = (tid >> 4) & 7, qk = tid >> 7;  // qk 0..3
            const float* wr = hwW + (size_t)(bg * 16 + rh) * 512 + qk * 128;
            const float* ibh = &inT[bi * 1024 + qk * 128];                // h0(t) quarter
            float acc = 0.f;
#pragma unroll 8
            for (int k = 0; k < 128; k += 4) {
                const float4 wv = *(const float4*)&wr[k];
                const float4 iv = *(const float4*)&ibh[k];
                acc += wv.x * iv.x + wv.y * iv.y + wv.z * iv.z + wv.w * iv.w;
            }
            hwred[tid] = acc;
            __syncthreads();
            if (tid < 128)
                stg_cg(hwzg + (size_t)((tid >> 4) & 7) * 512 + bg * 16 + (tid & 15),
                       hwred[tid] + hwred[tid + 128] + hwred[tid + 256] + hwred[tid + 384]);
        }
        if (more) {
            // restage inT = [x(t+1) | h0(t)]: h0 LDS->reg->LDS, x from global
            float4 h0a, h0b;
            {
                const float* src = &inT[sbi * 1024];
                h0a = *(const float4*)&src[part * 4];
                h0b = *(const float4*)&src[256 + part * 4];
            }
            const float* xp = x + ((size_t)(bb0 + sbi) * TT + (t + 1)) * DD;
            const float4 xa = *(const float4*)&xp[part * 4];
            const float4 xb = *(const float4*)&xp[256 + part * 4];
            __syncthreads();                 // all reads of inT (gemv1/hw/h0-save) done
            {
                float* d = &inT[sbi * 1024];
                *(float4*)&d[512 + part * 4] = h0a;
                *(float4*)&d[768 + part * 4] = h0b;
                *(float4*)&d[part * 4]       = xa;
                *(float4*)&d[256 + part * 4] = xb;
            }
            __syncthreads();
            float z;
            gemv_k8(w0t, inT, zr, bq, r, R0 + r, bq, z);
            stg_cg(z0g + (size_t)bq * 2048 + R0 + r, z);
        }
        group_barrier(gfl, ++ph, bg, tid);

        // ================= P_B: cell1(t) + out(t) + cell0(t+1) =================
        if (bg < 8) {
            const int b = bb0 + bg;
            float hv1;
            cell(z1g + (size_t)bg * 2048, gb1, lng1, lnb1, c1, h1ws + (size_t)b * 512, hv1, sred, tid);
            {
                const float hz = ldg_cg(hwzg + (size_t)bg * 512 + tid) + hwb_r;
                const float gt = 1.f / (1.f + expf(-hz));
                out[((size_t)b * TT + t) * HH + tid] = gt * hv1 + (1.f - gt) * hv0;
            }
            if (more) {
                cell(z0g + (size_t)bg * 2048, gb0, lng0, lnb0, c0, h0ws + (size_t)b * 512, hv0, sred, tid);
            } else {
                out[OUT_SZ + (size_t)b * 512 + tid]         = hv0;  // h_n[0]
                out[OUT_SZ + 32768 + (size_t)b * 512 + tid] = hv1;  // h_n[1]
                out[OUT_SZ + 65536 + (size_t)b * 512 + tid] = c0;   // c_n[0]
                out[OUT_SZ + 98304 + (size_t)b * 512 + tid] = c1;   // c_n[1]
            }
        }
        group_barrier(gfl, ++ph, bg, tid);
    } // t
}

extern "C" void kernel_launch(void* const* d_in, const int* in_sizes, int n_in,
                              void* d_out, int out_size, void* d_ws, size_t ws_size,
                              hipStream_t stream)
{
    (void)in_sizes; (void)n_in; (void)out_size; (void)ws_size;
    const float* x    = (const float*)d_in[0];
    const float* W0   = (const float*)d_in[1];
    const float* b0   = (const float*)d_in[2];
    const float* lng0 = (const float*)d_in[3];
    const float* lnb0 = (const float*)d_in[4];
    const float* W1   = (const float*)d_in[5];
    const float* b1   = (const float*)d_in[6];
    const float* lng1 = (const float*)d_in[7];
    const float* lnb1 = (const float*)d_in[8];
    const float* hwW  = (const float*)d_in[9];
    const float* hwb  = (const float*)d_in[10];
    float* out = (float*)d_out;
    float* ws  = (float*)d_ws;

    ln_lstm_init_kernel<<<dim3(256), dim3(256), 0, stream>>>(W0, W1, ws);
    LayerNormLSTMStack_55508157333865_kernel<<<dim3(NBLK), dim3(NTHR), 0, stream>>>(
        x, W0, b0, lng0, lnb0, W1, b1, lng1, lnb1, hwW, hwb, out, ws);
}

// Round 10
// 50057.571 us; speedup vs baseline: 1.1326x; 1.1326x over previous
//
#include <hip/hip_runtime.h>

#define TT 1024
#define BB 64
#define HH 512
#define DD 512
#define NBLK 256
#define NTHR 256
#define NGRP 8           // 8 batch groups x 8 rows; 32 blocks per group
#define BSTR 1536        // unified inT row stride: [x | h0 | h1]

// ---------------- ws layout (32-bit words), total 4,562,944 words = 18,251,776 B (R8-proven)
#define W0T4_OFF 0               // [256 kq][2048 R][4]  transposed-packed W0
#define W1T4_OFF 2097152         // same for W1
#define H0_OFF   4194304         // [64 b][512]  h0 single-buffered
#define H1_OFF   4227072         // [64 b][512]
#define Z0_OFF   4259840         // [8 grp][8 bi][2048]
#define Z1_OFF   4390912         // [8 grp][8 bi][2048]
#define HWZ_OFF  4521984         // [8 grp][8 bi][512]
#define FLG_OFF  4554752         // [8 grp][32 slot][32 words]  (128B stride)

// ======== cross-block access ========
// Loads: agent-relaxed (sc1) — read the coherence point (R7/R8-proven).
__device__ __forceinline__ float ldg_cg(const float* p) {
    return __hip_atomic_load(p, __ATOMIC_RELAXED, __HIP_MEMORY_SCOPE_AGENT);
}
__device__ __forceinline__ float4 ldg_cg4(const float* p) {
    const unsigned long long* q = (const unsigned long long*)p;
    unsigned long long a = __hip_atomic_load(q,     __ATOMIC_RELAXED, __HIP_MEMORY_SCOPE_AGENT);
    unsigned long long b = __hip_atomic_load(q + 1, __ATOMIC_RELAXED, __HIP_MEMORY_SCOPE_AGENT);
    float4 v;
    ((unsigned long long*)&v)[0] = a;
    ((unsigned long long*)&v)[1] = b;
    return v;
}
__device__ __forceinline__ unsigned ldg_cgu(const unsigned* p) {
    return __hip_atomic_load(p, __ATOMIC_RELAXED, __HIP_MEMORY_SCOPE_AGENT);
}
// Stores: SYSTEM-relaxed (sc0+sc1, write-through past L2) — keeps L2 clean so the
// release-barrier's dirty-line writeback is near-empty (R6 showed agent-relaxed
// stores park dirty in L2; R7's release flush is what made it correct but costly).
__device__ __forceinline__ void stg_wt(float* p, float v) {
    __hip_atomic_store(p, v, __ATOMIC_RELAXED, __HIP_MEMORY_SCOPE_SYSTEM);
}

// ======== group barrier: 32 blocks, flag-array, RELEASE-published (R7-proven) ========
__device__ __forceinline__ void group_barrier(unsigned* gfl, unsigned tgt, int slot, int tid)
{
    __syncthreads();
    if (tid == 0)
        __hip_atomic_store(&gfl[slot * 32], tgt, __ATOMIC_RELEASE, __HIP_MEMORY_SCOPE_AGENT);
    if (tid < 32) {
        while (ldg_cgu(&gfl[tid * 32]) < tgt) __builtin_amdgcn_s_sleep(1);
    }
    __syncthreads();
}

// ---------------- init: transpose-pack weights + zero h-state + flags ----------------
__global__ void ln_lstm_init_kernel(const float* __restrict__ W0, const float* __restrict__ W1,
                                    float* __restrict__ ws)
{
    const int stride = gridDim.x * blockDim.x;
    const int idx = blockIdx.x * blockDim.x + threadIdx.x;
    for (int i = idx; i < 2048 * 256; i += stride) {
        const int R = i & 2047, kq = i >> 11;
        const float4 v0 = *(const float4*)&W0[(size_t)R * 1024 + kq * 4];
        const float4 v1 = *(const float4*)&W1[(size_t)R * 1024 + kq * 4];
        *(float4*)&ws[W0T4_OFF + ((size_t)kq * 2048 + R) * 4] = v0;
        *(float4*)&ws[W1T4_OFF + ((size_t)kq * 2048 + R) * 4] = v1;
    }
    for (int i = idx; i < 65536; i += stride) ws[H0_OFF + i] = 0.f;    // h0 + h1
    unsigned* uw = (unsigned*)ws;
    for (int i = idx; i < 8192; i += stride) uw[FLG_OFF + i] = 0u;     // barrier flags
}

// ---------------- full-K GEMV off unified inT: 64 rows x 8 batches; K quartered ------
// Identical instruction mix to R8's gemv_k4 (16-deep W prefetch, LDS broadcast);
// only the inT row stride (1536) and K-offset (koff) differ.
__device__ __forceinline__ void gemv_k4u(const float4* __restrict__ wt, const float* __restrict__ inT,
                                         int koff, float* __restrict__ zr, int bq, int r, int Rrow,
                                         float& z0, float& z1)
{
    float a[8];
#pragma unroll
    for (int i = 0; i < 8; ++i) a[i] = 0.f;
    const float4* wp = wt + (size_t)(bq * 64) * 2048 + Rrow;
    const float* ib = inT + koff + bq * 256;
    for (int c = 0; c < 4; ++c) {
        float4 w[16];
#pragma unroll
        for (int i = 0; i < 16; ++i) w[i] = wp[(size_t)(c * 16 + i) * 2048];
#pragma unroll
        for (int i = 0; i < 16; ++i) {
            const int kk = c * 64 + i * 4;
#pragma unroll
            for (int bi = 0; bi < 8; ++bi) {
                const float4 iv = *(const float4*)&ib[bi * BSTR + kk];
                a[bi] += w[i].x * iv.x + w[i].y * iv.y + w[i].z * iv.z + w[i].w * iv.w;
            }
        }
    }
#pragma unroll
    for (int bi = 0; bi < 8; ++bi) zr[bq * 512 + bi * 64 + r] = a[bi];
    __syncthreads();
    z0 = 0.f; z1 = 0.f;
#pragma unroll
    for (int w2 = 0; w2 < 4; ++w2) {
        z0 += zr[w2 * 512 + bq * 64 + r];
        z1 += zr[w2 * 512 + (bq + 4) * 64 + r];
    }
}

// ---------------- block-local reductions (R8-proven, 4 waves) ----------------
__device__ __forceinline__ void block_reduce8(float v[8], float* sred, int tid)
{
#pragma unroll
    for (int off = 32; off > 0; off >>= 1)
#pragma unroll
        for (int k = 0; k < 8; ++k) v[k] += __shfl_down(v[k], off, 64);
    __syncthreads();
    if ((tid & 63) == 0) {
        const int wv = tid >> 6;
#pragma unroll
        for (int k = 0; k < 8; ++k) sred[k * 4 + wv] = v[k];
    }
    __syncthreads();
#pragma unroll
    for (int k = 0; k < 8; ++k)
        v[k] = sred[k * 4 + 0] + sred[k * 4 + 1] + sred[k * 4 + 2] + sred[k * 4 + 3];
}
__device__ __forceinline__ void block_reduce2(float& s1, float& s2, float* sred, int tid)
{
#pragma unroll
    for (int off = 32; off > 0; off >>= 1) {
        s1 += __shfl_down(s1, off, 64);
        s2 += __shfl_down(s2, off, 64);
    }
    __syncthreads();
    if ((tid & 63) == 0) {
        const int wv = tid >> 6;
        sred[wv] = s1; sred[4 + wv] = s2;
    }
    __syncthreads();
    s1 = sred[0] + sred[1] + sred[2] + sred[3];
    s2 = sred[4] + sred[5] + sred[6] + sred[7];
}

// ---------------- whole LSTM cell for one batch, fully block-local (R8-proven) -------
__device__ __forceinline__ void cell(const float* __restrict__ zg, const float* __restrict__ gb,
                                     const float* __restrict__ lng, const float* __restrict__ lnb,
                                     float cc[2], float* __restrict__ hws_b, float hv[2],
                                     float* sred, int tid)
{
    float z[4][2];
#pragma unroll
    for (int g = 0; g < 4; ++g) {
        z[g][0] = ldg_cg(zg + g * 512 + tid)       + gb[g * 512 + tid];
        z[g][1] = ldg_cg(zg + g * 512 + tid + 256) + gb[g * 512 + tid + 256];
    }
    float st[8];
#pragma unroll
    for (int g = 0; g < 4; ++g) {
        st[g]     = z[g][0] + z[g][1];
        st[4 + g] = z[g][0] * z[g][0] + z[g][1] * z[g][1];
    }
    block_reduce8(st, sred, tid);
    float act[4][2];
#pragma unroll
    for (int g = 0; g < 4; ++g) {
        const float mu = st[g] * (1.f / 512.f);
        const float rs = rsqrtf(st[4 + g] * (1.f / 512.f) - mu * mu + 1e-5f);
#pragma unroll
        for (int e = 0; e < 2; ++e) {
            const int j = tid + e * 256;
            const float a = (z[g][e] - mu) * rs * lng[g * 512 + j] + lnb[g * 512 + j];
            act[g][e] = (g == 2) ? tanhf(a) : 1.f / (1.f + expf(-a));
        }
    }
    float cn[2];
#pragma unroll
    for (int e = 0; e < 2; ++e) {
        cn[e] = act[1][e] * cc[e] + act[0][e] * act[2][e];   // f*c + i*g
        cc[e] = cn[e];
    }
    float s1 = cn[0] + cn[1];
    float s2 = cn[0] * cn[0] + cn[1] * cn[1];
    block_reduce2(s1, s2, sred, tid);
    const float mu = s1 * (1.f / 512.f);
    const float rs = rsqrtf(s2 * (1.f / 512.f) - mu * mu + 1e-5f);
#pragma unroll
    for (int e = 0; e < 2; ++e) {
        const int j = tid + e * 256;
        const float h = act[3][e] * tanhf((cn[e] - mu) * rs * lng[2048 + j] + lnb[2048 + j]);
        stg_wt(hws_b + j, h);
        hv[e] = h;
    }
}

__global__ __launch_bounds__(NTHR, 1)
void LayerNormLSTMStack_55508157333865_kernel(
    const float* __restrict__ x,
    const float* __restrict__ W0, const float* __restrict__ gb0,
    const float* __restrict__ lng0, const float* __restrict__ lnb0,
    const float* __restrict__ W1, const float* __restrict__ gb1,
    const float* __restrict__ lng1, const float* __restrict__ lnb1,
    const float* __restrict__ hwW, const float* __restrict__ hwb,
    float* __restrict__ out, float* __restrict__ ws)
{
    __shared__ __align__(16) float inT[8 * BSTR];   // 48 KB: [bi][ x(t+1) | h0(t) | h1(t-1) ]
    __shared__ __align__(16) float zr[4 * 512];     // 8 KB per-wave K-partials
    __shared__ float sred[32];
    __shared__ float hwred[256];

    const int tid = threadIdx.x;
    const int grp = blockIdx.x >> 5;        // batch group (8 rows)
    const int bg  = blockIdx.x & 31;        // slot in group
    const int bb0 = grp * 8;
    const int r = tid & 63, bq = tid >> 6;
    const int R0 = bg * 64;                 // this block's 64 GEMV rows

    const float4* w0t = (const float4*)(ws + W0T4_OFF);
    const float4* w1t = (const float4*)(ws + W1T4_OFF);
    float* h0ws  = ws + H0_OFF;
    float* h1ws  = ws + H1_OFF;
    float* z0g   = ws + Z0_OFF + grp * 16384;
    float* z1g   = ws + Z1_OFF + grp * 16384;
    float* hwzg  = ws + HWZ_OFF + grp * 4096;
    unsigned* gfl = (unsigned*)ws + FLG_OFF + grp * 1024;

    float c0[2] = {0.f, 0.f}, c1[2] = {0.f, 0.f};
    float hv0[2] = {0.f, 0.f};              // bg<8: h0(t+1) registers
    unsigned ph = 0;
    const size_t OUT_SZ = (size_t)BB * TT * HH;
    const int sbi = tid >> 5, part = tid & 31;   // staging: row sbi, lane part

    // ================= prologue: gemv0(0) ; cell0(0) =================
    {
        const float* xp = x + ((size_t)(bb0 + sbi) * TT + 0) * DD + part * 16;
        float* d = &inT[sbi * BSTR + part * 16];
        *(float4*)(d)      = *(const float4*)(xp);
        *(float4*)(d + 4)  = *(const float4*)(xp + 4);
        *(float4*)(d + 8)  = *(const float4*)(xp + 8);
        *(float4*)(d + 12) = *(const float4*)(xp + 12);
        float* dh = &inT[sbi * BSTR + 512 + part * 16];      // h0(-1)=0
        const float4 zz = make_float4(0.f, 0.f, 0.f, 0.f);
        *(float4*)(dh) = zz; *(float4*)(dh + 4) = zz; *(float4*)(dh + 8) = zz; *(float4*)(dh + 12) = zz;
    }
    __syncthreads();
    {
        float z0, z1;
        gemv_k4u(w0t, inT, 0, zr, bq, r, R0 + r, z0, z1);
        stg_wt(z0g + (size_t)bq * 2048 + R0 + r, z0);
        stg_wt(z0g + (size_t)(bq + 4) * 2048 + R0 + r, z1);
    }
    group_barrier(gfl, ++ph, bg, tid);
    if (bg < 8)
        cell(z0g + (size_t)bg * 2048, gb0, lng0, lnb0, c0, h0ws + (size_t)(bb0 + bg) * 512, hv0, sred, tid);
    group_barrier(gfl, ++ph, bg, tid);

    for (int t = 0; t < TT; ++t) {
        const bool more = (t + 1 < TT);
        const int tx = more ? (t + 1) : (TT - 1);   // clamped x index (last-step pad)

        // ===== P_A: single stage [x(t+1)|h0(t)|h1(t-1)] -> gemv1(t), hw(t), gemv0(t+1) =====
        {
            // x first (HBM latency hides under the MALL h loads)
            const float* xp = x + ((size_t)(bb0 + sbi) * TT + tx) * DD + part * 16;
            const float4 xa = *(const float4*)(xp);
            const float4 xb = *(const float4*)(xp + 4);
            const float4 xc = *(const float4*)(xp + 8);
            const float4 xd = *(const float4*)(xp + 12);
            const float* hp0 = h0ws + (size_t)(bb0 + sbi) * 512 + part * 16;
            const float4 h0a = ldg_cg4(hp0);
            const float4 h0b = ldg_cg4(hp0 + 4);
            const float4 h0c = ldg_cg4(hp0 + 8);
            const float4 h0d = ldg_cg4(hp0 + 12);
            const float* hp1 = h1ws + (size_t)(bb0 + sbi) * 512 + part * 16;
            const float4 h1a = ldg_cg4(hp1);
            const float4 h1b = ldg_cg4(hp1 + 4);
            const float4 h1c = ldg_cg4(hp1 + 8);
            const float4 h1d = ldg_cg4(hp1 + 12);
            float* d = &inT[sbi * BSTR + part * 16];
            *(float4*)(d)      = xa; *(float4*)(d + 4)  = xb;
            *(float4*)(d + 8)  = xc; *(float4*)(d + 12) = xd;
            float* dh0 = &inT[sbi * BSTR + 512 + part * 16];
            *(float4*)(dh0)      = h0a; *(float4*)(dh0 + 4)  = h0b;
            *(float4*)(dh0 + 8)  = h0c; *(float4*)(dh0 + 12) = h0d;
            float* dh1 = &inT[sbi * BSTR + 1024 + part * 16];
            *(float4*)(dh1)      = h1a; *(float4*)(dh1 + 4)  = h1b;
            *(float4*)(dh1 + 8)  = h1c; *(float4*)(dh1 + 12) = h1d;
        }
        __syncthreads();
        {
            float z0, z1;
            gemv_k4u(w1t, inT, 512, zr, bq, r, R0 + r, z0, z1);   // K = [h0|h1]
            stg_wt(z1g + (size_t)bq * 2048 + R0 + r, z0);
            stg_wt(z1g + (size_t)(bq + 4) * 2048 + R0 + r, z1);
        }
        // highway rows [bg*16,+16) x 8 batches off h0(t) (inT cols 512..1023)
        {
            const int rh = tid & 15, bi = (tid >> 4) & 7, hf = tid >> 7;
            const float* wr = hwW + (size_t)(bg * 16 + rh) * 512 + hf * 256;
            const float* ibh = &inT[bi * BSTR + 512 + hf * 256];
            float acc = 0.f;
#pragma unroll 8
            for (int k = 0; k < 256; k += 4) {
                const float4 wv = *(const float4*)&wr[k];
                const float4 iv = *(const float4*)&ibh[k];
                acc += wv.x * iv.x + wv.y * iv.y + wv.z * iv.z + wv.w * iv.w;
            }
            hwred[tid] = acc;
            __syncthreads();                  // also closes zr WAR (gemv1 reads done)
            if (tid < 128)
                stg_wt(hwzg + (size_t)((tid >> 4) & 7) * 512 + bg * 16 + (tid & 15),
                       hwred[tid] + hwred[tid + 128]);
        }
        if (more) {
            float z0, z1;
            gemv_k4u(w0t, inT, 0, zr, bq, r, R0 + r, z0, z1);     // K = [x|h0]
            stg_wt(z0g + (size_t)bq * 2048 + R0 + r, z0);
            stg_wt(z0g + (size_t)(bq + 4) * 2048 + R0 + r, z1);
        }
        group_barrier(gfl, ++ph, bg, tid);

        // ===== P_B: parallel cells — bg<8: cell0(t+1); bg 8..15: cell1(t)+out(t) =====
        if (bg < 8) {
            const int b = bb0 + bg;
            if (more) {
                cell(z0g + (size_t)bg * 2048, gb0, lng0, lnb0, c0, h0ws + (size_t)b * 512, hv0, sred, tid);
            } else {
#pragma unroll
                for (int e = 0; e < 2; ++e) {
                    const int j = tid + e * 256;
                    out[OUT_SZ + (size_t)b * 512 + j]         = hv0[e];  // h_n[0]
                    out[OUT_SZ + 65536 + (size_t)b * 512 + j] = c0[e];   // c_n[0]
                }
            }
        } else if (bg < 16) {
            const int bi = bg - 8;
            const int b = bb0 + bi;
            float hv1[2];
            cell(z1g + (size_t)bi * 2048, gb1, lng1, lnb1, c1, h1ws + (size_t)b * 512, hv1, sred, tid);
#pragma unroll
            for (int e = 0; e < 2; ++e) {
                const int j = tid + e * 256;
                const float hz = ldg_cg(hwzg + (size_t)bi * 512 + j) + hwb[j];
                const float gt = 1.f / (1.f + expf(-hz));
                const float h0v = inT[bi * BSTR + 512 + j];   // h0(t) from own staged inT
                out[((size_t)b * TT + t) * HH + j] = gt * hv1[e] + (1.f - gt) * h0v;
            }
            if (!more) {
#pragma unroll
                for (int e = 0; e < 2; ++e) {
                    const int j = tid + e * 256;
                    out[OUT_SZ + 32768 + (size_t)b * 512 + j] = hv1[e];  // h_n[1]
                    out[OUT_SZ + 98304 + (size_t)b * 512 + j] = c1[e];   // c_n[1]
                }
            }
        }
        group_barrier(gfl, ++ph, bg, tid);
    } // t
}

extern "C" void kernel_launch(void* const* d_in, const int* in_sizes, int n_in,
                              void* d_out, int out_size, void* d_ws, size_t ws_size,
                              hipStream_t stream)
{
    (void)in_sizes; (void)n_in; (void)out_size; (void)ws_size;
    const float* x    = (const float*)d_in[0];
    const float* W0   = (const float*)d_in[1];
    const float* b0   = (const float*)d_in[2];
    const float* lng0 = (const float*)d_in[3];
    const float* lnb0 = (const float*)d_in[4];
    const float* W1   = (const float*)d_in[5];
    const float* b1   = (const float*)d_in[6];
    const float* lng1 = (const float*)d_in[7];
    const float* lnb1 = (const float*)d_in[8];
    const float* hwW  = (const float*)d_in[9];
    const float* hwb  = (const float*)d_in[10];
    float* out = (float*)d_out;
    float* ws  = (float*)d_ws;

    ln_lstm_init_kernel<<<dim3(256), dim3(256), 0, stream>>>(W0, W1, ws);
    LayerNormLSTMStack_55508157333865_kernel<<<dim3(NBLK), dim3(NTHR), 0, stream>>>(
        x, W0, b0, lng0, lnb0, W1, b1, lng1, lnb1, hwW, hwb, out, ws);
}